// Round 5
// baseline (4217.916 us; speedup 1.0000x reference)
//
#include <hip/hip_runtime.h>
#include <math.h>

constexpr int B_ = 4;
constexpr int N_ = 512;

// ---------------------------------------------------------------------------
// Bit-faithful reimplementation of XLA:CPU's vectorized f32 exp/log
// (llvm_ir_runtime.cc GenerateVF32Exp/GenerateVF32Log, i.e. the Eigen/Cephes
// polynomials). MulAdd there is mul-then-add with separate roundings (no FMA,
// fast-math off) -> contract(off) pragmas here so hipcc can't fuse.
// ---------------------------------------------------------------------------
__device__ __forceinline__ float cephes_expf(float xin) {
#pragma clang fp contract(off)
    float x = fminf(xin, 88.3762626647950f);
    x = fmaxf(x, -88.3762626647949f);
    float fx = x * 1.44269504088896341f;   // cephes_LOG2EF (rounded to f32)
    fx = fx + 0.5f;
    fx = floorf(fx);
    float tmp = fx * 0.693359375f;         // cephes_exp_C1
    float z0  = fx * -2.12194440e-4f;      // cephes_exp_C2
    float r = x - tmp;
    r = r - z0;
    float zz = r * r;
    float y = 1.9875691500E-4f;            // p0
    y = y * r + 1.3981999507E-3f;          // p1
    y = y * r + 8.3334519073E-3f;          // p2
    y = y * r + 4.1665795894E-2f;          // p3
    y = y * r + 1.6666665459E-1f;          // p4
    y = y * r + 5.0000001201E-1f;          // p5
    y = y * zz + r;
    y = y + 1.0f;
    int n = (int)fx;                       // fx clamped -> convertible
    float p2n = __uint_as_float((unsigned)(n + 0x7f) << 23);
    float res = y * p2n;
    return fmaxf(res, xin);                // Eigen pexp tail (no-op in-domain)
}

__device__ __forceinline__ float cephes_logf(float t) {
#pragma clang fp contract(off)
    float xx = fmaxf(t, 1.17549435e-38f);  // min_norm_pos
    unsigned u = __float_as_uint(xx);
    int e_i = (int)(u >> 23) - 0x7f;
    float e = (float)e_i + 1.0f;
    float m = __uint_as_float((u & 0x807fffffu) | 0x3f000000u); // mant in [0.5,1)
    int mask = (m < 0.707106781186547524f); // cephes_SQRTHF
    float tmp1 = mask ? m : 0.0f;
    float x = m - 1.0f;
    e = e - (mask ? 1.0f : 0.0f);
    x = x + tmp1;
    float z = x * x;
    float y = 7.0376836292E-2f;            // p0
    y = y * x + -1.1514610310E-1f;         // p1
    y = y * x + 1.1676998740E-1f;          // p2
    y = y * x + -1.2420140846E-1f;         // p3
    y = y * x + 1.4249322787E-1f;          // p4
    y = y * x + -1.6668057665E-1f;         // p5
    y = y * x + 2.0000714765E-1f;          // p6
    y = y * x + -2.4999993993E-1f;         // p7
    y = y * x + 3.3333331174E-1f;          // p8
    y = y * x;
    y = y * z;
    y = e * -2.12194440e-4f + y;           // q1
    y = y - z * 0.5f;
    float res = x + y;
    res = res + e * 0.693359375f;          // q2
    return res;                            // inputs > 0: no special cases
}

// ---------------------------------------------------------------------------
// Kernel 0: per-(b,i) focal class cost, XLA:CPU expression order:
//   prob = 1/(1+cephes_exp(-x)); pow(.,2)->x*x (algsimp)
//   neg  = (0.75*(p*p)) * (-cephes_log((1-p)+1e-8))
//   pos  = (0.25*(om*om)) * (-cephes_log(p+1e-8))
// ---------------------------------------------------------------------------
__global__ __launch_bounds__(256) void class_cost_kernel(
    const float* __restrict__ logits, float* __restrict__ cc_out)
{
#pragma clang fp contract(off)
    int idx = blockIdx.x * 256 + threadIdx.x;   // 0 .. B*N-1
    if (idx >= B_ * N_) return;
    float x    = logits[idx];
    float e    = cephes_expf(-x);
    float prob = 1.0f / (1.0f + e);             // IEEE f32 div both sides
    float om   = 1.0f - prob;
    float p2   = prob * prob;
    float o2   = om * om;
    float lneg = cephes_logf(om   + 1e-8f);
    float lpos = cephes_logf(prob + 1e-8f);
    float neg  = (0.75f * p2) * (-lneg);
    float pos  = (0.25f * o2) * (-lpos);
    cc_out[idx] = pos - neg;
}

// ---------------------------------------------------------------------------
// Kernel 1: C[b][i][j] = cc[b][i] + (|dx| + |dy|)   (pure f32 IEEE)
// ---------------------------------------------------------------------------
__global__ __launch_bounds__(512) void cost_kernel(
    const float* __restrict__ cc,
    const float* __restrict__ pred_pts,
    const float* __restrict__ gt_pts,
    float* __restrict__ C)
{
    int blk = blockIdx.x;            // 0 .. B*N-1  (b,i)
    int b = blk >> 9;
    int i = blk & (N_ - 1);
    int j = threadIdx.x;

    const float2* pp2 = reinterpret_cast<const float2*>(pred_pts);
    const float2* gp2 = reinterpret_cast<const float2*>(gt_pts);
    float2 pp = pp2[b * N_ + i];
    float2 gp = gp2[b * N_ + j];
    float coord = fabsf(pp.x - gp.x) + fabsf(pp.y - gp.y);

    C[(size_t)b * N_ * N_ + (size_t)i * N_ + j] = cc[blk] + coord;
}

// ---------------------------------------------------------------------------
// Kernel 2: faithful replication of the reference _lsa (with its dead
// minv/way stores). One block per batch; thread t owns column t (v/used)
// and row t (u/in_chain). f64 ops in the reference's exact order.
// ---------------------------------------------------------------------------
__global__ __launch_bounds__(512) void solve_kernel(
    const float* __restrict__ C,
    float* __restrict__ pred_idx,
    float* __restrict__ gt_idx)
{
    int b = blockIdx.x;
    int t = threadIdx.x;
    const float* Cb = C + (size_t)b * N_ * N_;

    __shared__ double u_sh[N_];
    __shared__ double v_sh[N_];
    __shared__ int    p_col[N_];     // owner row of column, -1 = free
    __shared__ int    used[N_];
    __shared__ int    in_chain[N_];
    __shared__ double wval[8];
    __shared__ int    widx[8];
    __shared__ int    s_row, s_j1, s_done;
    __shared__ double s_delta;

    u_sh[t] = 0.0;
    v_sh[t] = 0.0;
    p_col[t] = -1;
    pred_idx[b * N_ + t] = (float)t;
    __syncthreads();

    for (int i = 0; i < N_; ++i) {
        used[t] = 0;
        in_chain[t] = (t == i) ? 1 : 0;
        if (t == 0) s_row = i;
        __syncthreads();

        while (true) {
            int row = s_row;
            double urow = u_sh[row];
            double cand = used[t] ? 1e18
                        : (((double)Cb[(size_t)row * N_ + t] - urow) - v_sh[t]);
            int idx = t;

            #pragma unroll
            for (int m = 1; m < 64; m <<= 1) {
                double vo = __shfl_xor(cand, m, 64);
                int    io = __shfl_xor(idx,  m, 64);
                if (vo < cand || (vo == cand && io < idx)) { cand = vo; idx = io; }
            }
            if ((t & 63) == 0) { wval[t >> 6] = cand; widx[t >> 6] = idx; }
            __syncthreads();                               // barrier 1

            if (t == 0) {
                double bv = wval[0]; int bi = widx[0];
                #pragma unroll
                for (int w = 1; w < 8; ++w) {
                    double vv = wval[w]; int ii = widx[w];
                    if (vv < bv || (vv == bv && ii < bi)) { bv = vv; bi = ii; }
                }
                s_j1 = bi; s_delta = bv;
            }
            __syncthreads();                               // barrier 2

            double delta = s_delta;
            if (in_chain[t]) u_sh[t] += delta;
            if (used[t])     v_sh[t] -= delta;
            __syncthreads();                               // barrier 3

            if (t == 0) {
                int j1 = s_j1;
                int owner = p_col[j1];
                if (owner < 0) { p_col[j1] = i; s_done = 1; }
                else {
                    used[j1] = 1;
                    in_chain[owner] = 1;
                    s_row = owner;
                    s_done = 0;
                }
            }
            __syncthreads();                               // barrier 4
            if (s_done) break;
        }
    }
    __syncthreads();
    gt_idx[b * N_ + p_col[t]] = (float)t;   // col_of_row[p[j]] = j
}

// ---------------------------------------------------------------------------
extern "C" void kernel_launch(void* const* d_in, const int* in_sizes, int n_in,
                              void* d_out, int out_size, void* d_ws, size_t ws_size,
                              hipStream_t stream)
{
    const float* logits   = (const float*)d_in[0];   // (B,N)   f32
    const float* pred_pts = (const float*)d_in[1];   // (B,N,2) f32
    const float* gt_pts   = (const float*)d_in[2];   // (B,N,2) f32
    // d_in[3] = gt_mask (all true) - unused

    float* out      = (float*)d_out;
    float* pred_idx = out;                    // B*N
    float* gt_idx   = out + B_ * N_;          // B*N
    float* C        = out + 2 * B_ * N_;      // B*N*N
    float* cc       = (float*)d_ws;           // B*N scratch

    class_cost_kernel<<<(B_ * N_ + 255) / 256, 256, 0, stream>>>(logits, cc);
    cost_kernel<<<B_ * N_, N_, 0, stream>>>(cc, pred_pts, gt_pts, C);
    solve_kernel<<<B_, N_, 0, stream>>>(C, pred_idx, gt_idx);
}

// Round 6
// 2506.297 us; speedup vs baseline: 1.6829x; 1.6829x over previous
//
#include <hip/hip_runtime.h>
#include <math.h>

constexpr int B_ = 4;
constexpr int N_ = 512;

// ---------------------------------------------------------------------------
// Bit-faithful reimplementation of XLA:CPU's vectorized f32 exp/log
// (llvm_ir_runtime.cc GenerateVF32Exp/GenerateVF32Log, i.e. the Eigen/Cephes
// polynomials). VERIFIED bit-exact vs the harness reference in round 5 —
// DO NOT CHANGE the arithmetic here.
// ---------------------------------------------------------------------------
__device__ __forceinline__ float cephes_expf(float xin) {
#pragma clang fp contract(off)
    float x = fminf(xin, 88.3762626647950f);
    x = fmaxf(x, -88.3762626647949f);
    float fx = x * 1.44269504088896341f;   // cephes_LOG2EF (rounded to f32)
    fx = fx + 0.5f;
    fx = floorf(fx);
    float tmp = fx * 0.693359375f;         // cephes_exp_C1
    float z0  = fx * -2.12194440e-4f;      // cephes_exp_C2
    float r = x - tmp;
    r = r - z0;
    float zz = r * r;
    float y = 1.9875691500E-4f;            // p0
    y = y * r + 1.3981999507E-3f;          // p1
    y = y * r + 8.3334519073E-3f;          // p2
    y = y * r + 4.1665795894E-2f;          // p3
    y = y * r + 1.6666665459E-1f;          // p4
    y = y * r + 5.0000001201E-1f;          // p5
    y = y * zz + r;
    y = y + 1.0f;
    int n = (int)fx;
    float p2n = __uint_as_float((unsigned)(n + 0x7f) << 23);
    float res = y * p2n;
    return fmaxf(res, xin);
}

__device__ __forceinline__ float cephes_logf(float t) {
#pragma clang fp contract(off)
    float xx = fmaxf(t, 1.17549435e-38f);  // min_norm_pos
    unsigned u = __float_as_uint(xx);
    int e_i = (int)(u >> 23) - 0x7f;
    float e = (float)e_i + 1.0f;
    float m = __uint_as_float((u & 0x807fffffu) | 0x3f000000u);
    int mask = (m < 0.707106781186547524f); // cephes_SQRTHF
    float tmp1 = mask ? m : 0.0f;
    float x = m - 1.0f;
    e = e - (mask ? 1.0f : 0.0f);
    x = x + tmp1;
    float z = x * x;
    float y = 7.0376836292E-2f;
    y = y * x + -1.1514610310E-1f;
    y = y * x + 1.1676998740E-1f;
    y = y * x + -1.2420140846E-1f;
    y = y * x + 1.4249322787E-1f;
    y = y * x + -1.6668057665E-1f;
    y = y * x + 2.0000714765E-1f;
    y = y * x + -2.4999993993E-1f;
    y = y * x + 3.3333331174E-1f;
    y = y * x;
    y = y * z;
    y = e * -2.12194440e-4f + y;
    y = y - z * 0.5f;
    float res = x + y;
    res = res + e * 0.693359375f;
    return res;
}

// ---------------------------------------------------------------------------
// Kernel 0: per-(b,i) focal class cost  (bit-exact, verified round 5)
// ---------------------------------------------------------------------------
__global__ __launch_bounds__(256) void class_cost_kernel(
    const float* __restrict__ logits, float* __restrict__ cc_out)
{
#pragma clang fp contract(off)
    int idx = blockIdx.x * 256 + threadIdx.x;
    if (idx >= B_ * N_) return;
    float x    = logits[idx];
    float e    = cephes_expf(-x);
    float prob = 1.0f / (1.0f + e);
    float om   = 1.0f - prob;
    float p2   = prob * prob;
    float o2   = om * om;
    float lneg = cephes_logf(om   + 1e-8f);
    float lpos = cephes_logf(prob + 1e-8f);
    float neg  = (0.75f * p2) * (-lneg);
    float pos  = (0.25f * o2) * (-lpos);
    cc_out[idx] = pos - neg;
}

// ---------------------------------------------------------------------------
// Kernel 1: C[b][i][j] = cc[b][i] + (|dx| + |dy|)   (bit-exact, verified)
// ---------------------------------------------------------------------------
__global__ __launch_bounds__(512) void cost_kernel(
    const float* __restrict__ cc,
    const float* __restrict__ pred_pts,
    const float* __restrict__ gt_pts,
    float* __restrict__ C)
{
    int blk = blockIdx.x;
    int b = blk >> 9;
    int i = blk & (N_ - 1);
    int j = threadIdx.x;

    const float2* pp2 = reinterpret_cast<const float2*>(pred_pts);
    const float2* gp2 = reinterpret_cast<const float2*>(gt_pts);
    float2 pp = pp2[b * N_ + i];
    float2 gp = gp2[b * N_ + j];
    float coord = fabsf(pp.x - gp.x) + fabsf(pp.y - gp.y);

    C[(size_t)b * N_ * N_ + (size_t)i * N_ + j] = cc[blk] + coord;
}

// ---------------------------------------------------------------------------
// DPP helpers: wave64 min-reduce ending in lane 63 (row_shr 1/2/4/8 +
// row_bcast15 + row_bcast31). bound_ctrl=false keeps `old` for invalid
// source lanes = identity for min. All-lanes-active by construction.
// ---------------------------------------------------------------------------
template<int CTRL>
__device__ __forceinline__ uint32_t dpp32(uint32_t x) {
    return (uint32_t)__builtin_amdgcn_update_dpp((int)x, (int)x, CTRL, 0xF, 0xF, false);
}
template<int CTRL>
__device__ __forceinline__ uint64_t dpp64(uint64_t x) {
    uint32_t lo = dpp32<CTRL>((uint32_t)x);
    uint32_t hi = dpp32<CTRL>((uint32_t)(x >> 32));
    return ((uint64_t)hi << 32) | lo;
}
#define MIN64_STEP(CTRL) { uint64_t o = dpp64<CTRL>(acc); acc = (o < acc) ? o : acc; }
#define MIN32_STEP(CTRL) { uint32_t o = dpp32<CTRL>(jc);  jc  = (o < jc)  ? o : jc; }

// Sortable-u64 key: order(key) == order(f64), bijective (no NaN, no -0.0 by
// construction of the candidate arithmetic).
__device__ __forceinline__ uint64_t f64_key(double d) {
    uint64_t b = (uint64_t)__double_as_longlong(d);
    return b ^ ((b >> 63) ? 0xFFFFFFFFFFFFFFFFull : 0x8000000000000000ull);
}

// ---------------------------------------------------------------------------
// Kernel 2: reference _lsa replica, single-wave-per-batch, all state in
// registers. Lane t owns columns/rows {4t..4t+3, 256+4t..256+4t+3}
// (slot k -> index ((k>>2)<<8) | (t<<2) | (k&3)).
// Semantics identical to the round-5 verified kernel:
//  - candidates: ((double)C[row][j] - u[row]) - v[j], used -> +INF
//  - argmin with global first-index tie-break (phase A: exact f64 min via
//    u64-key DPP reduce; phase B: min column index among exact ties)
//  - eager sequential u/v updates in reference order (bit-exact f64 sums);
//    walk reads provably never see intra-walk updates, so no sync needed.
// ---------------------------------------------------------------------------
__global__ __launch_bounds__(64) void solve_kernel(
    const float* __restrict__ C,
    float* __restrict__ pred_idx,
    float* __restrict__ gt_idx)
{
    const int b = blockIdx.x;
    const int t = threadIdx.x;
    const float* Cb = C + (size_t)b * N_ * N_;

    double u_reg[8], v_reg[8];
    int pc[8];
    #pragma unroll
    for (int k = 0; k < 8; ++k) { u_reg[k] = 0.0; v_reg[k] = 0.0; pc[k] = -1; }

    #pragma unroll
    for (int k = 0; k < 8; ++k) {
        int j = t + 64 * k;
        pred_idx[b * N_ + j] = (float)j;
    }

    // uniform-index read of u[r]: slot-select (unrolled cndmask) + readlane
    auto read_u = [&](int r) -> double {
        int sl = ((((unsigned)r) >> 8) << 2) | (r & 3);
        int ln = (((unsigned)r) >> 2) & 63;
        double us = u_reg[0];
        #pragma unroll
        for (int k = 1; k < 8; ++k) us = (sl == k) ? u_reg[k] : us;
        uint64_t ub = (uint64_t)__double_as_longlong(us);
        uint32_t lo = (uint32_t)__builtin_amdgcn_readlane((int)(uint32_t)ub, ln);
        uint32_t hi = (uint32_t)__builtin_amdgcn_readlane((int)(uint32_t)(ub >> 32), ln);
        return __longlong_as_double((long long)(((uint64_t)hi << 32) | lo));
    };

    for (int i = 0; i < N_; ++i) {
        unsigned used_m = 0, chain_m = 0;
        {   // row i joins the chain (receives every delta of this walk)
            int sl = ((((unsigned)i) >> 8) << 2) | (i & 3);
            chain_m |= (t == ((((unsigned)i) >> 2) & 63)) ? (1u << sl) : 0u;
        }
        int row = i;
        double urow = read_u(row);

        for (;;) {
            // ---- row load: 2 x dwordx4, fully coalesced (2 KB row, L2-hot)
            const float4* rp = reinterpret_cast<const float4*>(Cb + ((size_t)row << 9));
            float4 ca = rp[t];
            float4 cb = rp[t + 64];
            float cv[8] = {ca.x, ca.y, ca.z, ca.w, cb.x, cb.y, cb.z, cb.w};

            // ---- candidates -> sortable keys (used -> max key)
            uint64_t kk[8];
            #pragma unroll
            for (int k = 0; k < 8; ++k) {
                double cand = (((double)cv[k]) - urow) - v_reg[k];
                uint64_t key = f64_key(cand);
                kk[k] = ((used_m >> k) & 1) ? 0xFFFFFFFFFFFFFFFFull : key;
            }
            // local argmin tree, ascending-j order, ties -> left (lower j)
            int jj0 = (t << 2);            // slots 0..3 -> j = 4t+k
            uint64_t m0k = (kk[1] < kk[0]) ? kk[1] : kk[0];
            int      m0j = (kk[1] < kk[0]) ? (jj0 | 1) : jj0;
            uint64_t m1k = (kk[3] < kk[2]) ? kk[3] : kk[2];
            int      m1j = (kk[3] < kk[2]) ? (jj0 | 3) : (jj0 | 2);
            uint64_t m2k = (kk[5] < kk[4]) ? kk[5] : kk[4];
            int      m2j = (kk[5] < kk[4]) ? (256 | jj0 | 1) : (256 | jj0);
            uint64_t m3k = (kk[7] < kk[6]) ? kk[7] : kk[6];
            int      m3j = (kk[7] < kk[6]) ? (256 | jj0 | 3) : (256 | jj0 | 2);
            uint64_t n0k = (m1k < m0k) ? m1k : m0k;
            int      n0j = (m1k < m0k) ? m1j : m0j;
            uint64_t n1k = (m3k < m2k) ? m3k : m2k;
            int      n1j = (m3k < m2k) ? m3j : m2j;
            uint64_t bk  = (n1k < n0k) ? n1k : n0k;
            int      bj  = (n1k < n0k) ? n1j : n0j;

            // ---- phase A: exact global min value (u64 key) via DPP
            uint64_t acc = bk;
            MIN64_STEP(0x111) MIN64_STEP(0x112) MIN64_STEP(0x114)
            MIN64_STEP(0x118) MIN64_STEP(0x142) MIN64_STEP(0x143)
            uint32_t mlo = (uint32_t)__builtin_amdgcn_readlane((int)(uint32_t)acc, 63);
            uint32_t mhi = (uint32_t)__builtin_amdgcn_readlane((int)(uint32_t)(acc >> 32), 63);
            uint64_t M = ((uint64_t)mhi << 32) | mlo;

            // ---- phase B: smallest column index among exact ties
            uint32_t jc = (bk == M) ? (uint32_t)bj : 0x7FFFFFFFu;
            MIN32_STEP(0x111) MIN32_STEP(0x112) MIN32_STEP(0x114)
            MIN32_STEP(0x118) MIN32_STEP(0x142) MIN32_STEP(0x143)
            int j1 = __builtin_amdgcn_readlane((int)jc, 63);

            // ---- delta (exact inverse of the key map; uniform scalar)
            uint64_t db = (M >> 63) ? (M ^ 0x8000000000000000ull) : ~M;
            double delta = __longlong_as_double((long long)db);

            // ---- eager sequential potential updates (reference order);
            // identity adds are bitwise no-ops (u,v never -0.0)
            #pragma unroll
            for (int k = 0; k < 8; ++k) {
                u_reg[k] += ((chain_m >> k) & 1) ? delta : 0.0;
                v_reg[k] -= ((used_m  >> k) & 1) ? delta : 0.0;
            }

            // ---- owner lookup: p_col[j1] (uniform slot select + readlane)
            int slot  = ((((unsigned)j1) >> 8) << 2) | (j1 & 3);
            int lane1 = (((unsigned)j1) >> 2) & 63;
            int sel = pc[0];
            #pragma unroll
            for (int k = 1; k < 8; ++k) sel = (slot == k) ? pc[k] : sel;
            int owner = __builtin_amdgcn_readlane(sel, lane1);

            if (owner < 0) {                    // free column: assign & stop
                bool mine = (t == lane1);
                #pragma unroll
                for (int k = 0; k < 8; ++k) pc[k] = (mine && slot == k) ? i : pc[k];
                break;
            }
            // occupied: mark visited, owner joins chain, hop
            used_m |= (t == lane1) ? (1u << slot) : 0u;
            {
                int so = ((((unsigned)owner) >> 8) << 2) | (owner & 3);
                chain_m |= (t == ((((unsigned)owner) >> 2) & 63)) ? (1u << so) : 0u;
            }
            row = owner;
            urow = read_u(row);
        }
    }

    // col_of_row[p_col[j]] = j
    #pragma unroll
    for (int k = 0; k < 8; ++k) {
        int j = ((k >> 2) << 8) | (t << 2) | (k & 3);
        gt_idx[b * N_ + pc[k]] = (float)j;
    }
}

// ---------------------------------------------------------------------------
extern "C" void kernel_launch(void* const* d_in, const int* in_sizes, int n_in,
                              void* d_out, int out_size, void* d_ws, size_t ws_size,
                              hipStream_t stream)
{
    const float* logits   = (const float*)d_in[0];   // (B,N)   f32
    const float* pred_pts = (const float*)d_in[1];   // (B,N,2) f32
    const float* gt_pts   = (const float*)d_in[2];   // (B,N,2) f32
    // d_in[3] = gt_mask (all true) - unused

    float* out      = (float*)d_out;
    float* pred_idx = out;                    // B*N
    float* gt_idx   = out + B_ * N_;          // B*N
    float* C        = out + 2 * B_ * N_;      // B*N*N
    float* cc       = (float*)d_ws;           // B*N scratch

    class_cost_kernel<<<(B_ * N_ + 255) / 256, 256, 0, stream>>>(logits, cc);
    cost_kernel<<<B_ * N_, N_, 0, stream>>>(cc, pred_pts, gt_pts, C);
    solve_kernel<<<B_, 64, 0, stream>>>(C, pred_idx, gt_idx);
}

// Round 7
// 2488.778 us; speedup vs baseline: 1.6948x; 1.0070x over previous
//
#include <hip/hip_runtime.h>
#include <math.h>

constexpr int B_ = 4;
constexpr int N_ = 512;

// ---------------------------------------------------------------------------
// Bit-faithful XLA:CPU Cephes f32 exp/log — VERIFIED bit-exact round 5.
// DO NOT CHANGE the arithmetic here.
// ---------------------------------------------------------------------------
__device__ __forceinline__ float cephes_expf(float xin) {
#pragma clang fp contract(off)
    float x = fminf(xin, 88.3762626647950f);
    x = fmaxf(x, -88.3762626647949f);
    float fx = x * 1.44269504088896341f;
    fx = fx + 0.5f;
    fx = floorf(fx);
    float tmp = fx * 0.693359375f;
    float z0  = fx * -2.12194440e-4f;
    float r = x - tmp;
    r = r - z0;
    float zz = r * r;
    float y = 1.9875691500E-4f;
    y = y * r + 1.3981999507E-3f;
    y = y * r + 8.3334519073E-3f;
    y = y * r + 4.1665795894E-2f;
    y = y * r + 1.6666665459E-1f;
    y = y * r + 5.0000001201E-1f;
    y = y * zz + r;
    y = y + 1.0f;
    int n = (int)fx;
    float p2n = __uint_as_float((unsigned)(n + 0x7f) << 23);
    float res = y * p2n;
    return fmaxf(res, xin);
}

__device__ __forceinline__ float cephes_logf(float t) {
#pragma clang fp contract(off)
    float xx = fmaxf(t, 1.17549435e-38f);
    unsigned u = __float_as_uint(xx);
    int e_i = (int)(u >> 23) - 0x7f;
    float e = (float)e_i + 1.0f;
    float m = __uint_as_float((u & 0x807fffffu) | 0x3f000000u);
    int mask = (m < 0.707106781186547524f);
    float tmp1 = mask ? m : 0.0f;
    float x = m - 1.0f;
    e = e - (mask ? 1.0f : 0.0f);
    x = x + tmp1;
    float z = x * x;
    float y = 7.0376836292E-2f;
    y = y * x + -1.1514610310E-1f;
    y = y * x + 1.1676998740E-1f;
    y = y * x + -1.2420140846E-1f;
    y = y * x + 1.4249322787E-1f;
    y = y * x + -1.6668057665E-1f;
    y = y * x + 2.0000714765E-1f;
    y = y * x + -2.4999993993E-1f;
    y = y * x + 3.3333331174E-1f;
    y = y * x;
    y = y * z;
    y = e * -2.12194440e-4f + y;
    y = y - z * 0.5f;
    float res = x + y;
    res = res + e * 0.693359375f;
    return res;
}

// ---------------------------------------------------------------------------
// Kernel 0 / Kernel 1: cost matrix — bit-exact, verified round 5. UNCHANGED.
// ---------------------------------------------------------------------------
__global__ __launch_bounds__(256) void class_cost_kernel(
    const float* __restrict__ logits, float* __restrict__ cc_out)
{
#pragma clang fp contract(off)
    int idx = blockIdx.x * 256 + threadIdx.x;
    if (idx >= B_ * N_) return;
    float x    = logits[idx];
    float e    = cephes_expf(-x);
    float prob = 1.0f / (1.0f + e);
    float om   = 1.0f - prob;
    float p2   = prob * prob;
    float o2   = om * om;
    float lneg = cephes_logf(om   + 1e-8f);
    float lpos = cephes_logf(prob + 1e-8f);
    float neg  = (0.75f * p2) * (-lneg);
    float pos  = (0.25f * o2) * (-lpos);
    cc_out[idx] = pos - neg;
}

__global__ __launch_bounds__(512) void cost_kernel(
    const float* __restrict__ cc,
    const float* __restrict__ pred_pts,
    const float* __restrict__ gt_pts,
    float* __restrict__ C)
{
    int blk = blockIdx.x;
    int b = blk >> 9;
    int i = blk & (N_ - 1);
    int j = threadIdx.x;

    const float2* pp2 = reinterpret_cast<const float2*>(pred_pts);
    const float2* gp2 = reinterpret_cast<const float2*>(gt_pts);
    float2 pp = pp2[b * N_ + i];
    float2 gp = gp2[b * N_ + j];
    float coord = fabsf(pp.x - gp.x) + fabsf(pp.y - gp.y);

    C[(size_t)b * N_ * N_ + (size_t)i * N_ + j] = cc[blk] + coord;
}

// ---------------------------------------------------------------------------
// DPP helpers (network verified in round 6's passing kernel).
// ---------------------------------------------------------------------------
template<int CTRL>
__device__ __forceinline__ uint32_t dpp32(uint32_t x) {
    return (uint32_t)__builtin_amdgcn_update_dpp((int)x, (int)x, CTRL, 0xF, 0xF, false);
}

__device__ __forceinline__ uint64_t f64_key(double d) {
    uint64_t b = (uint64_t)__double_as_longlong(d);
    return b ^ ((b >> 63) ? 0xFFFFFFFFFFFFFFFFull : 0x8000000000000000ull);
}

__device__ __forceinline__ double readlane_f64(double d, int lane) {
    unsigned long long ll = (unsigned long long)__double_as_longlong(d);
    unsigned lo = (unsigned)__builtin_amdgcn_readlane((int)(unsigned)ll, lane);
    unsigned hi = (unsigned)__builtin_amdgcn_readlane((int)(unsigned)(ll >> 32), lane);
    return __longlong_as_double((long long)(((unsigned long long)hi << 32) | lo));
}

#define SLOT_OF(x) ((int)(((((unsigned)(x)) >> 8) << 2) | (((unsigned)(x)) & 3u)))
#define LANE_OF(x) ((int)((((unsigned)(x)) >> 2) & 63u))

// one lexicographic (key, j) DPP min step: min key, tie -> min j
#define RSTEP(CTRL) {                                                          \
    uint32_t klo_o = dpp32<CTRL>(klo);                                         \
    uint32_t khi_o = dpp32<CTRL>(khi);                                         \
    uint32_t j_o   = dpp32<CTRL>(jj);                                          \
    uint64_t ko = ((uint64_t)khi_o << 32) | klo_o;                             \
    uint64_t kc = ((uint64_t)khi   << 32) | klo;                               \
    bool lt = (ko < kc) || (ko == kc && j_o < jj);                             \
    klo = lt ? klo_o : klo; khi = lt ? khi_o : khi; jj = lt ? j_o : jj;        \
}

// ---------------------------------------------------------------------------
// Kernel 2: reference _lsa replica, one wave per batch, ALL state in named
// scalar VGPRs (no arrays -> nothing for PromoteAlloca to demote to LDS).
// Lane t owns slots k=0..7 <-> column/row index ((k>>2)<<8)|(t<<2)|(k&3).
// Bit-exact semantics proven in rounds 5/6; u/v eager updates are off the
// serial chain (intra-walk candidate reads never observe them).
// ---------------------------------------------------------------------------
__global__ __launch_bounds__(64) void solve_kernel(
    const float* __restrict__ C,
    float* __restrict__ pred_idx,
    float* __restrict__ gt_idx)
{
    const int b = blockIdx.x;
    const int t = threadIdx.x;
    const float4* rp0 = reinterpret_cast<const float4*>(C + (size_t)b * N_ * N_);

    double u0=0.0,u1=0.0,u2=0.0,u3=0.0,u4=0.0,u5=0.0,u6=0.0,u7=0.0;
    double v0=0.0,v1=0.0,v2=0.0,v3=0.0,v4=0.0,v5=0.0,v6=0.0,v7=0.0;
    int    p0=-1,p1=-1,p2=-1,p3=-1,p4=-1,p5=-1,p6=-1,p7=-1;

    #pragma unroll
    for (int k = 0; k < 8; ++k)
        pred_idx[b * N_ + t + 64 * k] = (float)(t + 64 * k);

    const uint32_t jj0 = (uint32_t)(t << 2);

    auto read_u_at = [&](int r) -> double {
        int sl = SLOT_OF(r), ln = LANE_OF(r);
        double x0 = (sl & 1) ? u1 : u0;
        double x1 = (sl & 1) ? u3 : u2;
        double x2 = (sl & 1) ? u5 : u4;
        double x3 = (sl & 1) ? u7 : u6;
        double y0 = (sl & 2) ? x1 : x0;
        double y1 = (sl & 2) ? x3 : x2;
        double z  = (sl & 4) ? y1 : y0;
        return readlane_f64(z, ln);
    };

    for (int i = 0; i < N_; ++i) {
        unsigned used_m  = 0u;
        unsigned chain_m = (t == LANE_OF(i)) ? (1u << SLOT_OF(i)) : 0u;
        int row = i;
        double urow = read_u_at(row);

        for (;;) {
            // ---- row load: 2 x dwordx4, coalesced, L2-resident
            const float4* rp = rp0 + (row << 7);     // row * 512/4
            float4 ca = rp[t];
            float4 cb = rp[t + 64];

            // ---- candidates -> sortable keys (used -> max key)
            uint64_t q0 = (used_m & 0x01u) ? ~0ull : f64_key(((double)ca.x - urow) - v0);
            uint64_t q1 = (used_m & 0x02u) ? ~0ull : f64_key(((double)ca.y - urow) - v1);
            uint64_t q2 = (used_m & 0x04u) ? ~0ull : f64_key(((double)ca.z - urow) - v2);
            uint64_t q3 = (used_m & 0x08u) ? ~0ull : f64_key(((double)ca.w - urow) - v3);
            uint64_t q4 = (used_m & 0x10u) ? ~0ull : f64_key(((double)cb.x - urow) - v4);
            uint64_t q5 = (used_m & 0x20u) ? ~0ull : f64_key(((double)cb.y - urow) - v5);
            uint64_t q6 = (used_m & 0x40u) ? ~0ull : f64_key(((double)cb.z - urow) - v6);
            uint64_t q7 = (used_m & 0x80u) ? ~0ull : f64_key(((double)cb.w - urow) - v7);

            // ---- local 8->1 lexicographic tree (ties -> lower j)
            uint64_t m0k = (q1 < q0) ? q1 : q0;  uint32_t m0j = (q1 < q0) ? (jj0|1u) : jj0;
            uint64_t m1k = (q3 < q2) ? q3 : q2;  uint32_t m1j = (q3 < q2) ? (jj0|3u) : (jj0|2u);
            uint64_t m2k = (q5 < q4) ? q5 : q4;  uint32_t m2j = (q5 < q4) ? (256u|jj0|1u) : (256u|jj0);
            uint64_t m3k = (q7 < q6) ? q7 : q6;  uint32_t m3j = (q7 < q6) ? (256u|jj0|3u) : (256u|jj0|2u);
            uint64_t n0k = (m1k < m0k) ? m1k : m0k;  uint32_t n0j = (m1k < m0k) ? m1j : m0j;
            uint64_t n1k = (m3k < m2k) ? m3k : m2k;  uint32_t n1j = (m3k < m2k) ? m3j : m2j;
            uint64_t bk  = (n1k < n0k) ? n1k : n0k;  uint32_t bj  = (n1k < n0k) ? n1j : n0j;

            // ---- single wave64 lexicographic DPP min-reduce -> lane 63
            uint32_t klo = (uint32_t)bk, khi = (uint32_t)(bk >> 32), jj = bj;
            RSTEP(0x111) RSTEP(0x112) RSTEP(0x114)
            RSTEP(0x118) RSTEP(0x142) RSTEP(0x143)
            int j1 = __builtin_amdgcn_readlane((int)jj, 63);
            uint32_t Mlo = (uint32_t)__builtin_amdgcn_readlane((int)klo, 63);
            uint32_t Mhi = (uint32_t)__builtin_amdgcn_readlane((int)khi, 63);
            uint64_t M = ((uint64_t)Mhi << 32) | Mlo;

            // ---- delta (inverse key map) — off the serial chain
            uint64_t db = (M >> 63) ? (M ^ 0x8000000000000000ull) : ~M;
            double delta = __longlong_as_double((long long)db);

            // ---- eager sequential u/v updates (reference order, bit-exact;
            //      +0.0 identities are bitwise no-ops, no -0.0 possible)
            u0 += (chain_m & 0x01u) ? delta : 0.0;
            u1 += (chain_m & 0x02u) ? delta : 0.0;
            u2 += (chain_m & 0x04u) ? delta : 0.0;
            u3 += (chain_m & 0x08u) ? delta : 0.0;
            u4 += (chain_m & 0x10u) ? delta : 0.0;
            u5 += (chain_m & 0x20u) ? delta : 0.0;
            u6 += (chain_m & 0x40u) ? delta : 0.0;
            u7 += (chain_m & 0x80u) ? delta : 0.0;
            v0 -= (used_m  & 0x01u) ? delta : 0.0;
            v1 -= (used_m  & 0x02u) ? delta : 0.0;
            v2 -= (used_m  & 0x04u) ? delta : 0.0;
            v3 -= (used_m  & 0x08u) ? delta : 0.0;
            v4 -= (used_m  & 0x10u) ? delta : 0.0;
            v5 -= (used_m  & 0x20u) ? delta : 0.0;
            v6 -= (used_m  & 0x40u) ? delta : 0.0;
            v7 -= (used_m  & 0x80u) ? delta : 0.0;

            // ---- owner lookup p_col[j1] (binary select + readlane)
            int slot1 = SLOT_OF(j1), lane1 = LANE_OF(j1);
            int a0 = (slot1 & 1) ? p1 : p0;
            int a1 = (slot1 & 1) ? p3 : p2;
            int a2 = (slot1 & 1) ? p5 : p4;
            int a3 = (slot1 & 1) ? p7 : p6;
            int b0 = (slot1 & 2) ? a1 : a0;
            int b1 = (slot1 & 2) ? a3 : a2;
            int zz = (slot1 & 4) ? b1 : b0;
            int owner = __builtin_amdgcn_readlane(zz, lane1);

            if (owner < 0) {                      // free column: assign, stop
                bool mine = (t == lane1);
                p0 = (mine && slot1 == 0) ? i : p0;
                p1 = (mine && slot1 == 1) ? i : p1;
                p2 = (mine && slot1 == 2) ? i : p2;
                p3 = (mine && slot1 == 3) ? i : p3;
                p4 = (mine && slot1 == 4) ? i : p4;
                p5 = (mine && slot1 == 5) ? i : p5;
                p6 = (mine && slot1 == 6) ? i : p6;
                p7 = (mine && slot1 == 7) ? i : p7;
                break;
            }
            used_m  |= (t == lane1)         ? (1u << slot1)         : 0u;
            chain_m |= (t == LANE_OF(owner)) ? (1u << SLOT_OF(owner)) : 0u;
            row = owner;
            urow = read_u_at(row);
        }
    }

    // col_of_row[p_col[j]] = j
    gt_idx[b * N_ + p0] = (float)(jj0);
    gt_idx[b * N_ + p1] = (float)(jj0 | 1u);
    gt_idx[b * N_ + p2] = (float)(jj0 | 2u);
    gt_idx[b * N_ + p3] = (float)(jj0 | 3u);
    gt_idx[b * N_ + p4] = (float)(256u | jj0);
    gt_idx[b * N_ + p5] = (float)(256u | jj0 | 1u);
    gt_idx[b * N_ + p6] = (float)(256u | jj0 | 2u);
    gt_idx[b * N_ + p7] = (float)(256u | jj0 | 3u);
}

// ---------------------------------------------------------------------------
extern "C" void kernel_launch(void* const* d_in, const int* in_sizes, int n_in,
                              void* d_out, int out_size, void* d_ws, size_t ws_size,
                              hipStream_t stream)
{
    const float* logits   = (const float*)d_in[0];   // (B,N)   f32
    const float* pred_pts = (const float*)d_in[1];   // (B,N,2) f32
    const float* gt_pts   = (const float*)d_in[2];   // (B,N,2) f32
    // d_in[3] = gt_mask (all true) - unused

    float* out      = (float*)d_out;
    float* pred_idx = out;                    // B*N
    float* gt_idx   = out + B_ * N_;          // B*N
    float* C        = out + 2 * B_ * N_;      // B*N*N
    float* cc       = (float*)d_ws;           // B*N scratch

    class_cost_kernel<<<(B_ * N_ + 255) / 256, 256, 0, stream>>>(logits, cc);
    cost_kernel<<<B_ * N_, N_, 0, stream>>>(cc, pred_pts, gt_pts, C);
    solve_kernel<<<B_, 64, 0, stream>>>(C, pred_idx, gt_idx);
}

// Round 8
// 2035.528 us; speedup vs baseline: 2.0721x; 1.2227x over previous
//
#include <hip/hip_runtime.h>
#include <math.h>

constexpr int B_ = 4;
constexpr int N_ = 512;

// ---------------------------------------------------------------------------
// Bit-faithful XLA:CPU Cephes f32 exp/log — VERIFIED bit-exact round 5.
// DO NOT CHANGE the arithmetic here.
// ---------------------------------------------------------------------------
__device__ __forceinline__ float cephes_expf(float xin) {
#pragma clang fp contract(off)
    float x = fminf(xin, 88.3762626647950f);
    x = fmaxf(x, -88.3762626647949f);
    float fx = x * 1.44269504088896341f;
    fx = fx + 0.5f;
    fx = floorf(fx);
    float tmp = fx * 0.693359375f;
    float z0  = fx * -2.12194440e-4f;
    float r = x - tmp;
    r = r - z0;
    float zz = r * r;
    float y = 1.9875691500E-4f;
    y = y * r + 1.3981999507E-3f;
    y = y * r + 8.3334519073E-3f;
    y = y * r + 4.1665795894E-2f;
    y = y * r + 1.6666665459E-1f;
    y = y * r + 5.0000001201E-1f;
    y = y * zz + r;
    y = y + 1.0f;
    int n = (int)fx;
    float p2n = __uint_as_float((unsigned)(n + 0x7f) << 23);
    float res = y * p2n;
    return fmaxf(res, xin);
}

__device__ __forceinline__ float cephes_logf(float t) {
#pragma clang fp contract(off)
    float xx = fmaxf(t, 1.17549435e-38f);
    unsigned u = __float_as_uint(xx);
    int e_i = (int)(u >> 23) - 0x7f;
    float e = (float)e_i + 1.0f;
    float m = __uint_as_float((u & 0x807fffffu) | 0x3f000000u);
    int mask = (m < 0.707106781186547524f);
    float tmp1 = mask ? m : 0.0f;
    float x = m - 1.0f;
    e = e - (mask ? 1.0f : 0.0f);
    x = x + tmp1;
    float z = x * x;
    float y = 7.0376836292E-2f;
    y = y * x + -1.1514610310E-1f;
    y = y * x + 1.1676998740E-1f;
    y = y * x + -1.2420140846E-1f;
    y = y * x + 1.4249322787E-1f;
    y = y * x + -1.6668057665E-1f;
    y = y * x + 2.0000714765E-1f;
    y = y * x + -2.4999993993E-1f;
    y = y * x + 3.3333331174E-1f;
    y = y * x;
    y = y * z;
    y = e * -2.12194440e-4f + y;
    y = y - z * 0.5f;
    float res = x + y;
    res = res + e * 0.693359375f;
    return res;
}

// ---------------------------------------------------------------------------
// Kernel 0 / Kernel 1: cost matrix — bit-exact, verified round 5. UNCHANGED.
// ---------------------------------------------------------------------------
__global__ __launch_bounds__(256) void class_cost_kernel(
    const float* __restrict__ logits, float* __restrict__ cc_out)
{
#pragma clang fp contract(off)
    int idx = blockIdx.x * 256 + threadIdx.x;
    if (idx >= B_ * N_) return;
    float x    = logits[idx];
    float e    = cephes_expf(-x);
    float prob = 1.0f / (1.0f + e);
    float om   = 1.0f - prob;
    float p2   = prob * prob;
    float o2   = om * om;
    float lneg = cephes_logf(om   + 1e-8f);
    float lpos = cephes_logf(prob + 1e-8f);
    float neg  = (0.75f * p2) * (-lneg);
    float pos  = (0.25f * o2) * (-lpos);
    cc_out[idx] = pos - neg;
}

__global__ __launch_bounds__(512) void cost_kernel(
    const float* __restrict__ cc,
    const float* __restrict__ pred_pts,
    const float* __restrict__ gt_pts,
    float* __restrict__ C)
{
    int blk = blockIdx.x;
    int b = blk >> 9;
    int i = blk & (N_ - 1);
    int j = threadIdx.x;

    const float2* pp2 = reinterpret_cast<const float2*>(pred_pts);
    const float2* gp2 = reinterpret_cast<const float2*>(gt_pts);
    float2 pp = pp2[b * N_ + i];
    float2 gp = gp2[b * N_ + j];
    float coord = fabsf(pp.x - gp.x) + fabsf(pp.y - gp.y);

    C[(size_t)b * N_ * N_ + (size_t)i * N_ + j] = cc[blk] + coord;
}

// ---------------------------------------------------------------------------
// DPP / lane helpers (DPP network verified in rounds 6/7).
// ---------------------------------------------------------------------------
template<int CTRL>
__device__ __forceinline__ uint32_t dpp32(uint32_t x) {
    return (uint32_t)__builtin_amdgcn_update_dpp((int)x, (int)x, CTRL, 0xF, 0xF, false);
}

__device__ __forceinline__ uint64_t f64_key(double d) {
    uint64_t b = (uint64_t)__double_as_longlong(d);
    return b ^ ((b >> 63) ? 0xFFFFFFFFFFFFFFFFull : 0x8000000000000000ull);
}

__device__ __forceinline__ double readlane_f64(double d, int lane) {
    unsigned long long ll = (unsigned long long)__double_as_longlong(d);
    unsigned lo = (unsigned)__builtin_amdgcn_readlane((int)(unsigned)ll, lane);
    unsigned hi = (unsigned)__builtin_amdgcn_readlane((int)(unsigned)(ll >> 32), lane);
    return __longlong_as_double((long long)(((unsigned long long)hi << 32) | lo));
}

// value-only u64 min DPP step (reduce result lands in lane 63)
#define VSTEP(CTRL) {                                                          \
    uint32_t lo_o = dpp32<CTRL>(klo);                                          \
    uint32_t hi_o = dpp32<CTRL>(khi);                                          \
    uint64_t ko = ((uint64_t)hi_o << 32) | lo_o;                               \
    uint64_t kc = ((uint64_t)khi  << 32) | klo;                                \
    bool lt = (ko < kc);                                                       \
    klo = lt ? lo_o : klo; khi = lt ? hi_o : khi;                              \
}

// ---------------------------------------------------------------------------
// Kernel 2: reference _lsa replica, one wave per batch, all state in named
// scalar VGPRs. Lane t owns columns/rows 8t..8t+7 (slot k -> index 8t+k) —
// j is monotone in (lane, slot), so global first-index tie-break =
// (lowest lane via ballot+ctz) x (lowest slot via local tree tie-direction).
// Changes vs round 7 (all latency, zero semantics):
//   * L2-warm pass: stream the batch's 1 MB C once (1 dword / 128B line) so
//     walk row loads hit the local XCD L2 instead of L3/HBM.
//   * value-only DPP reduce + ballot tie-break (shorter serial chain).
//   * hop path issues the next row load BEFORE u/v bookkeeping (updates are
//     provably unobservable intra-walk -> overlap the load latency).
//   * prefetch of next walk-start row i+1 during walk i.
// ---------------------------------------------------------------------------
__global__ __launch_bounds__(64) void solve_kernel(
    const float* __restrict__ C,
    float* __restrict__ pred_idx,
    float* __restrict__ gt_idx)
{
    const int b = blockIdx.x;
    const int t = threadIdx.x;
    const float*  Cs  = C + (size_t)b * N_ * N_;
    const float4* rp0 = reinterpret_cast<const float4*>(Cs);

    // ---- prefetch row 0 (walk 0 start) first in the queue
    float4 pa = rp0[2 * t];
    float4 pb = rp0[2 * t + 1];

    // ---- L2 warm: touch every 128B line of this batch's C (8192 lines,
    // 128 loads/lane, 8 independent accumulators to pipeline)
    {
        float w0 = 0.f, w1 = 0.f, w2 = 0.f, w3 = 0.f,
              w4 = 0.f, w5 = 0.f, w6 = 0.f, w7 = 0.f;
        for (int it = 0; it < 128; it += 8) {
            w0 += Cs[(t + 64 * (it + 0)) * 32];
            w1 += Cs[(t + 64 * (it + 1)) * 32];
            w2 += Cs[(t + 64 * (it + 2)) * 32];
            w3 += Cs[(t + 64 * (it + 3)) * 32];
            w4 += Cs[(t + 64 * (it + 4)) * 32];
            w5 += Cs[(t + 64 * (it + 5)) * 32];
            w6 += Cs[(t + 64 * (it + 6)) * 32];
            w7 += Cs[(t + 64 * (it + 7)) * 32];
        }
        float wsum = ((w0 + w1) + (w2 + w3)) + ((w4 + w5) + (w6 + w7));
        __asm__ volatile("" : : "v"(wsum));   // sink: keep the loads
    }

    double u0=0.0,u1=0.0,u2=0.0,u3=0.0,u4=0.0,u5=0.0,u6=0.0,u7=0.0;
    double v0=0.0,v1=0.0,v2=0.0,v3=0.0,v4=0.0,v5=0.0,v6=0.0,v7=0.0;
    int    p0=-1,p1=-1,p2=-1,p3=-1,p4=-1,p5=-1,p6=-1,p7=-1;

    #pragma unroll
    for (int k = 0; k < 8; ++k)
        pred_idx[b * N_ + t + 64 * k] = (float)(t + 64 * k);

    // u[r]: lane r>>3, slot r&7  (binary select tree + readlane)
    auto read_u_at = [&](int r) -> double {
        int sl = r & 7, ln = r >> 3;
        double x0 = (sl & 1) ? u1 : u0;
        double x1 = (sl & 1) ? u3 : u2;
        double x2 = (sl & 1) ? u5 : u4;
        double x3 = (sl & 1) ? u7 : u6;
        double y0 = (sl & 2) ? x1 : x0;
        double y1 = (sl & 2) ? x3 : x2;
        double z  = (sl & 4) ? y1 : y0;
        return readlane_f64(z, ln);
    };

    for (int i = 0; i < N_; ++i) {
        unsigned used_m  = 0u;
        unsigned chain_m = (t == (i >> 3)) ? (1u << (i & 7)) : 0u;
        double urow = read_u_at(i);
        float4 ca = pa, cb = pb;

        // prefetch next walk's start row (consumed at walk i+1)
        {
            int nxt = (i + 1 < N_) ? (i + 1) : i;
            const float4* rpn = rp0 + (nxt << 7);
            pa = rpn[2 * t];
            pb = rpn[2 * t + 1];
        }

        for (;;) {
            // ---- candidates -> sortable keys (used -> max key)
            uint64_t q0 = (used_m & 0x01u) ? ~0ull : f64_key(((double)ca.x - urow) - v0);
            uint64_t q1 = (used_m & 0x02u) ? ~0ull : f64_key(((double)ca.y - urow) - v1);
            uint64_t q2 = (used_m & 0x04u) ? ~0ull : f64_key(((double)ca.z - urow) - v2);
            uint64_t q3 = (used_m & 0x08u) ? ~0ull : f64_key(((double)ca.w - urow) - v3);
            uint64_t q4 = (used_m & 0x10u) ? ~0ull : f64_key(((double)cb.x - urow) - v4);
            uint64_t q5 = (used_m & 0x20u) ? ~0ull : f64_key(((double)cb.y - urow) - v5);
            uint64_t q6 = (used_m & 0x40u) ? ~0ull : f64_key(((double)cb.z - urow) - v6);
            uint64_t q7 = (used_m & 0x80u) ? ~0ull : f64_key(((double)cb.w - urow) - v7);

            // ---- local 8->1 tree (ties -> lower slot = lower j)
            uint64_t ka = (q1 < q0) ? q1 : q0;  uint32_t sa = (q1 < q0) ? 1u : 0u;
            uint64_t kb = (q3 < q2) ? q3 : q2;  uint32_t sb = (q3 < q2) ? 3u : 2u;
            uint64_t kx = (q5 < q4) ? q5 : q4;  uint32_t sx = (q5 < q4) ? 5u : 4u;
            uint64_t kd = (q7 < q6) ? q7 : q6;  uint32_t sd = (q7 < q6) ? 7u : 6u;
            uint64_t ke = (kb < ka) ? kb : ka;  uint32_t se = (kb < ka) ? sb : sa;
            uint64_t kf = (kd < kx) ? kd : kx;  uint32_t sf = (kd < kx) ? sd : sx;
            uint64_t bk = (kf < ke) ? kf : ke;  uint32_t bslot = (kf < ke) ? sf : se;

            // ---- wave64 value-only u64 min (DPP), result in lane 63
            uint32_t klo = (uint32_t)bk, khi = (uint32_t)(bk >> 32);
            VSTEP(0x111) VSTEP(0x112) VSTEP(0x114)
            VSTEP(0x118) VSTEP(0x142) VSTEP(0x143)
            uint32_t Mlo = (uint32_t)__builtin_amdgcn_readlane((int)klo, 63);
            uint32_t Mhi = (uint32_t)__builtin_amdgcn_readlane((int)khi, 63);
            uint64_t M = ((uint64_t)Mhi << 32) | Mlo;

            // ---- tie-break: lowest lane holding the min -> lowest j
            unsigned long long tied = __ballot(bk == M);
            int lane1 = (int)__builtin_ctzll(tied);
            int slot1 = __builtin_amdgcn_readlane((int)bslot, lane1);

            // ---- owner lookup p_col[j1] (select tree + readlane)
            int a0 = (slot1 & 1) ? p1 : p0;
            int a1 = (slot1 & 1) ? p3 : p2;
            int a2 = (slot1 & 1) ? p5 : p4;
            int a3 = (slot1 & 1) ? p7 : p6;
            int b0 = (slot1 & 2) ? a1 : a0;
            int b1 = (slot1 & 2) ? a3 : a2;
            int zz = (slot1 & 4) ? b1 : b0;
            int owner = __builtin_amdgcn_readlane(zz, lane1);

            // ---- delta (inverse key map; uniform)
            uint64_t db = (M >> 63) ? (M ^ 0x8000000000000000ull) : ~M;
            double delta = __longlong_as_double((long long)db);

            if (owner < 0) {     // free column: terminal-step updates + assign
                u0 += (chain_m & 0x01u) ? delta : 0.0;
                u1 += (chain_m & 0x02u) ? delta : 0.0;
                u2 += (chain_m & 0x04u) ? delta : 0.0;
                u3 += (chain_m & 0x08u) ? delta : 0.0;
                u4 += (chain_m & 0x10u) ? delta : 0.0;
                u5 += (chain_m & 0x20u) ? delta : 0.0;
                u6 += (chain_m & 0x40u) ? delta : 0.0;
                u7 += (chain_m & 0x80u) ? delta : 0.0;
                v0 -= (used_m  & 0x01u) ? delta : 0.0;
                v1 -= (used_m  & 0x02u) ? delta : 0.0;
                v2 -= (used_m  & 0x04u) ? delta : 0.0;
                v3 -= (used_m  & 0x08u) ? delta : 0.0;
                v4 -= (used_m  & 0x10u) ? delta : 0.0;
                v5 -= (used_m  & 0x20u) ? delta : 0.0;
                v6 -= (used_m  & 0x40u) ? delta : 0.0;
                v7 -= (used_m  & 0x80u) ? delta : 0.0;
                bool mine = (t == lane1);
                p0 = (mine && slot1 == 0) ? i : p0;
                p1 = (mine && slot1 == 1) ? i : p1;
                p2 = (mine && slot1 == 2) ? i : p2;
                p3 = (mine && slot1 == 3) ? i : p3;
                p4 = (mine && slot1 == 4) ? i : p4;
                p5 = (mine && slot1 == 5) ? i : p5;
                p6 = (mine && slot1 == 6) ? i : p6;
                p7 = (mine && slot1 == 7) ? i : p7;
                break;
            }

            // ---- hop: issue next row load FIRST, bookkeeping in its shadow
            {
                const float4* rp = rp0 + (owner << 7);
                ca = rp[2 * t];
                cb = rp[2 * t + 1];
            }
            urow = read_u_at(owner);   // owner's u untouched by this step

            u0 += (chain_m & 0x01u) ? delta : 0.0;
            u1 += (chain_m & 0x02u) ? delta : 0.0;
            u2 += (chain_m & 0x04u) ? delta : 0.0;
            u3 += (chain_m & 0x08u) ? delta : 0.0;
            u4 += (chain_m & 0x10u) ? delta : 0.0;
            u5 += (chain_m & 0x20u) ? delta : 0.0;
            u6 += (chain_m & 0x40u) ? delta : 0.0;
            u7 += (chain_m & 0x80u) ? delta : 0.0;
            v0 -= (used_m  & 0x01u) ? delta : 0.0;
            v1 -= (used_m  & 0x02u) ? delta : 0.0;
            v2 -= (used_m  & 0x04u) ? delta : 0.0;
            v3 -= (used_m  & 0x08u) ? delta : 0.0;
            v4 -= (used_m  & 0x10u) ? delta : 0.0;
            v5 -= (used_m  & 0x20u) ? delta : 0.0;
            v6 -= (used_m  & 0x40u) ? delta : 0.0;
            v7 -= (used_m  & 0x80u) ? delta : 0.0;

            used_m  |= (t == lane1)        ? (1u << slot1)       : 0u;
            chain_m |= (t == (owner >> 3)) ? (1u << (owner & 7)) : 0u;
        }
    }

    // col_of_row[p_col[j]] = j   (j = 8t + k)
    const int j0 = t << 3;
    gt_idx[b * N_ + p0] = (float)(j0);
    gt_idx[b * N_ + p1] = (float)(j0 + 1);
    gt_idx[b * N_ + p2] = (float)(j0 + 2);
    gt_idx[b * N_ + p3] = (float)(j0 + 3);
    gt_idx[b * N_ + p4] = (float)(j0 + 4);
    gt_idx[b * N_ + p5] = (float)(j0 + 5);
    gt_idx[b * N_ + p6] = (float)(j0 + 6);
    gt_idx[b * N_ + p7] = (float)(j0 + 7);
}

// ---------------------------------------------------------------------------
extern "C" void kernel_launch(void* const* d_in, const int* in_sizes, int n_in,
                              void* d_out, int out_size, void* d_ws, size_t ws_size,
                              hipStream_t stream)
{
    const float* logits   = (const float*)d_in[0];   // (B,N)   f32
    const float* pred_pts = (const float*)d_in[1];   // (B,N,2) f32
    const float* gt_pts   = (const float*)d_in[2];   // (B,N,2) f32
    // d_in[3] = gt_mask (all true) - unused

    float* out      = (float*)d_out;
    float* pred_idx = out;                    // B*N
    float* gt_idx   = out + B_ * N_;          // B*N
    float* C        = out + 2 * B_ * N_;      // B*N*N
    float* cc       = (float*)d_ws;           // B*N scratch

    class_cost_kernel<<<(B_ * N_ + 255) / 256, 256, 0, stream>>>(logits, cc);
    cost_kernel<<<B_ * N_, N_, 0, stream>>>(cc, pred_pts, gt_pts, C);
    solve_kernel<<<B_, 64, 0, stream>>>(C, pred_idx, gt_idx);
}

// Round 11
// 1647.071 us; speedup vs baseline: 2.5609x; 1.2358x over previous
//
#include <hip/hip_runtime.h>
#include <math.h>

constexpr int B_ = 4;
constexpr int N_ = 512;

// ---------------------------------------------------------------------------
// Bit-faithful XLA:CPU Cephes f32 exp/log - VERIFIED bit-exact round 5.
// DO NOT CHANGE the arithmetic here.
// ---------------------------------------------------------------------------
__device__ __forceinline__ float cephes_expf(float xin) {
#pragma clang fp contract(off)
    float x = fminf(xin, 88.3762626647950f);
    x = fmaxf(x, -88.3762626647949f);
    float fx = x * 1.44269504088896341f;
    fx = fx + 0.5f;
    fx = floorf(fx);
    float tmp = fx * 0.693359375f;
    float z0  = fx * -2.12194440e-4f;
    float r = x - tmp;
    r = r - z0;
    float zz = r * r;
    float y = 1.9875691500E-4f;
    y = y * r + 1.3981999507E-3f;
    y = y * r + 8.3334519073E-3f;
    y = y * r + 4.1665795894E-2f;
    y = y * r + 1.6666665459E-1f;
    y = y * r + 5.0000001201E-1f;
    y = y * zz + r;
    y = y + 1.0f;
    int n = (int)fx;
    float p2n = __uint_as_float((unsigned)(n + 0x7f) << 23);
    float res = y * p2n;
    return fmaxf(res, xin);
}

__device__ __forceinline__ float cephes_logf(float t) {
#pragma clang fp contract(off)
    float xx = fmaxf(t, 1.17549435e-38f);
    unsigned u = __float_as_uint(xx);
    int e_i = (int)(u >> 23) - 0x7f;
    float e = (float)e_i + 1.0f;
    float m = __uint_as_float((u & 0x807fffffu) | 0x3f000000u);
    int mask = (m < 0.707106781186547524f);
    float tmp1 = mask ? m : 0.0f;
    float x = m - 1.0f;
    e = e - (mask ? 1.0f : 0.0f);
    x = x + tmp1;
    float z = x * x;
    float y = 7.0376836292E-2f;
    y = y * x + -1.1514610310E-1f;
    y = y * x + 1.1676998740E-1f;
    y = y * x + -1.2420140846E-1f;
    y = y * x + 1.4249322787E-1f;
    y = y * x + -1.6668057665E-1f;
    y = y * x + 2.0000714765E-1f;
    y = y * x + -2.4999993993E-1f;
    y = y * x + 3.3333331174E-1f;
    y = y * x;
    y = y * z;
    y = e * -2.12194440e-4f + y;
    y = y - z * 0.5f;
    float res = x + y;
    res = res + e * 0.693359375f;
    return res;
}

// ---------------------------------------------------------------------------
// Kernel 0 / Kernel 1: cost matrix - bit-exact, verified round 5. UNCHANGED.
// (C must still be produced: it is output 2.)
// ---------------------------------------------------------------------------
__global__ __launch_bounds__(256) void class_cost_kernel(
    const float* __restrict__ logits, float* __restrict__ cc_out)
{
#pragma clang fp contract(off)
    int idx = blockIdx.x * 256 + threadIdx.x;
    if (idx >= B_ * N_) return;
    float x    = logits[idx];
    float e    = cephes_expf(-x);
    float prob = 1.0f / (1.0f + e);
    float om   = 1.0f - prob;
    float p2   = prob * prob;
    float o2   = om * om;
    float lneg = cephes_logf(om   + 1e-8f);
    float lpos = cephes_logf(prob + 1e-8f);
    float neg  = (0.75f * p2) * (-lneg);
    float pos  = (0.25f * o2) * (-lpos);
    cc_out[idx] = pos - neg;
}

__global__ __launch_bounds__(512) void cost_kernel(
    const float* __restrict__ cc,
    const float* __restrict__ pred_pts,
    const float* __restrict__ gt_pts,
    float* __restrict__ C)
{
    int blk = blockIdx.x;
    int b = blk >> 9;
    int i = blk & (N_ - 1);
    int j = threadIdx.x;

    const float2* pp2 = reinterpret_cast<const float2*>(pred_pts);
    const float2* gp2 = reinterpret_cast<const float2*>(gt_pts);
    float2 pp = pp2[b * N_ + i];
    float2 gp = gp2[b * N_ + j];
    float coord = fabsf(pp.x - gp.x) + fabsf(pp.y - gp.y);

    C[(size_t)b * N_ * N_ + (size_t)i * N_ + j] = cc[blk] + coord;
}

// ---------------------------------------------------------------------------
// DPP / lane helpers (row_shr 1/2/4/8 + row_bcast15/31 network verified in
// rounds 6-8; result lands in lane 63; bound_ctrl=false => invalid lanes
// keep old value = identity for min).
// ---------------------------------------------------------------------------
template<int CTRL>
__device__ __forceinline__ uint32_t dpp32(uint32_t x) {
    return (uint32_t)__builtin_amdgcn_update_dpp((int)x, (int)x, CTRL, 0xF, 0xF, false);
}
#define UMINSTEP(X, CTRL) { uint32_t o_ = dpp32<CTRL>(X); X = (o_ < X) ? o_ : X; }

__device__ __forceinline__ uint32_t wave_umin_lane63(uint32_t x) {
    UMINSTEP(x, 0x111) UMINSTEP(x, 0x112) UMINSTEP(x, 0x114)
    UMINSTEP(x, 0x118) UMINSTEP(x, 0x142) UMINSTEP(x, 0x143)
    return x;
}

__device__ __forceinline__ double readlane_f64(double d, int lane) {
    unsigned long long ll = (unsigned long long)__double_as_longlong(d);
    unsigned lo = (unsigned)__builtin_amdgcn_readlane((int)(unsigned)ll, lane);
    unsigned hi = (unsigned)__builtin_amdgcn_readlane((int)(unsigned)(ll >> 32), lane);
    return __longlong_as_double((long long)(((unsigned long long)hi << 32) | lo));
}

// ---------------------------------------------------------------------------
// Kernel 2: reference _lsa replica, one wave per batch, ZERO memory ops in
// the walk loop. Lane t owns rows/columns 8t..8t+7 (slot k -> index 8t+k).
// C-row values are RECOMPUTED per step from register-resident generators
// (cc[r], pred[r], gt[j]) with cost_kernel's exact f32 op order => bit-equal
// to the stored C. Candidate/u/v arithmetic is f64 in reference order
// (bit-exact, verified rounds 5-8). First-index tie-break: f64 local tree
// prefers lower slot; cross-lane two-phase (hi,lo) min + ballot+ctz prefers
// lower lane; j = 8*lane + slot is monotone => global argmin first-index.
// -0.0 provably never occurs => f64 compare order == sortable-key order.
// ---------------------------------------------------------------------------
__global__ __launch_bounds__(64) void solve_kernel(
    const float* __restrict__ cc_in,
    const float* __restrict__ pred_pts,
    const float* __restrict__ gt_pts,
    float* __restrict__ pred_idx,
    float* __restrict__ gt_idx)
{
    const int b = blockIdx.x;
    const int t = threadIdx.x;

    // ---- load generators into registers (one-time)
    const float2* pq = reinterpret_cast<const float2*>(pred_pts) + b * N_;
    const float2* gq = reinterpret_cast<const float2*>(gt_pts)   + b * N_;
    const float*  cq = cc_in + b * N_;
    const int base = t << 3;

    float2 r0 = pq[base + 0], r1 = pq[base + 1], r2 = pq[base + 2], r3 = pq[base + 3];
    float2 r4 = pq[base + 4], r5 = pq[base + 5], r6 = pq[base + 6], r7 = pq[base + 7];
    float2 g0 = gq[base + 0], g1 = gq[base + 1], g2 = gq[base + 2], g3 = gq[base + 3];
    float2 g4 = gq[base + 4], g5 = gq[base + 5], g6 = gq[base + 6], g7 = gq[base + 7];
    float  c0 = cq[base + 0], c1 = cq[base + 1], c2 = cq[base + 2], c3 = cq[base + 3];
    float  c4 = cq[base + 4], c5 = cq[base + 5], c6 = cq[base + 6], c7 = cq[base + 7];

    double u0=0.0,u1=0.0,u2=0.0,u3=0.0,u4=0.0,u5=0.0,u6=0.0,u7=0.0;
    double v0=0.0,v1=0.0,v2=0.0,v3=0.0,v4=0.0,v5=0.0,v6=0.0,v7=0.0;
    int    p0=-1,p1=-1,p2=-1,p3=-1,p4=-1,p5=-1,p6=-1,p7=-1;

    #pragma unroll
    for (int k = 0; k < 8; ++k)
        pred_idx[b * N_ + t + 64 * k] = (float)(t + 64 * k);

    // select slot sl (0..7) out of 8 per-lane values (depth-3 cndmask tree)
    #define SEL8F(sl, x0,x1,x2,x3,x4,x5,x6,x7, out) {                      \
        float a0_=((sl)&1)?(x1):(x0), a1_=((sl)&1)?(x3):(x2);              \
        float a2_=((sl)&1)?(x5):(x4), a3_=((sl)&1)?(x7):(x6);              \
        float b0_=((sl)&2)?a1_:a0_,   b1_=((sl)&2)?a3_:a2_;                \
        out = ((sl)&4)?b1_:b0_; }
    #define SEL8I(sl, x0,x1,x2,x3,x4,x5,x6,x7, out) {                      \
        int a0_=((sl)&1)?(x1):(x0), a1_=((sl)&1)?(x3):(x2);                \
        int a2_=((sl)&1)?(x5):(x4), a3_=((sl)&1)?(x7):(x6);                \
        int b0_=((sl)&2)?a1_:a0_,   b1_=((sl)&2)?a3_:a2_;                  \
        out = ((sl)&4)?b1_:b0_; }
    #define SEL8D(sl, x0,x1,x2,x3,x4,x5,x6,x7, out) {                      \
        double a0_=((sl)&1)?(x1):(x0), a1_=((sl)&1)?(x3):(x2);             \
        double a2_=((sl)&1)?(x5):(x4), a3_=((sl)&1)?(x7):(x6);             \
        double b0_=((sl)&2)?a1_:a0_,   b1_=((sl)&2)?a3_:a2_;               \
        out = ((sl)&4)?b1_:b0_; }

    // fetch row-r scalars (px,py,cc,u) - r wave-uniform
    float px_r, py_r, cc_r; double urow;
    #define ROW_SCALARS(r) {                                               \
        int sl_ = (r) & 7, ln_ = (r) >> 3;                                 \
        float sx_, sy_, sc_; double su_;                                   \
        SEL8F(sl_, r0.x,r1.x,r2.x,r3.x,r4.x,r5.x,r6.x,r7.x, sx_);          \
        SEL8F(sl_, r0.y,r1.y,r2.y,r3.y,r4.y,r5.y,r6.y,r7.y, sy_);          \
        SEL8F(sl_, c0,c1,c2,c3,c4,c5,c6,c7, sc_);                          \
        SEL8D(sl_, u0,u1,u2,u3,u4,u5,u6,u7, su_);                          \
        px_r = __uint_as_float((unsigned)__builtin_amdgcn_readlane(        \
                   (int)__float_as_uint(sx_), ln_));                       \
        py_r = __uint_as_float((unsigned)__builtin_amdgcn_readlane(        \
                   (int)__float_as_uint(sy_), ln_));                       \
        cc_r = __uint_as_float((unsigned)__builtin_amdgcn_readlane(        \
                   (int)__float_as_uint(sc_), ln_));                       \
        urow = readlane_f64(su_, ln_); }

    const float INF32 = __uint_as_float(0x7F800000u);

    for (int i = 0; i < N_; ++i) {
        unsigned used_m  = 0u;
        unsigned chain_m = (t == (i >> 3)) ? (1u << (i & 7)) : 0u;
        ROW_SCALARS(i);

        for (;;) {
#pragma clang fp contract(off)
            // ---- recompute this row's 8 C values (bit-equal to cost_kernel)
            float w0 = cc_r + (fabsf(px_r - g0.x) + fabsf(py_r - g0.y));
            float w1 = cc_r + (fabsf(px_r - g1.x) + fabsf(py_r - g1.y));
            float w2 = cc_r + (fabsf(px_r - g2.x) + fabsf(py_r - g2.y));
            float w3 = cc_r + (fabsf(px_r - g3.x) + fabsf(py_r - g3.y));
            float w4 = cc_r + (fabsf(px_r - g4.x) + fabsf(py_r - g4.y));
            float w5 = cc_r + (fabsf(px_r - g5.x) + fabsf(py_r - g5.y));
            float w6 = cc_r + (fabsf(px_r - g6.x) + fabsf(py_r - g6.y));
            float w7 = cc_r + (fabsf(px_r - g7.x) + fabsf(py_r - g7.y));
            // used columns -> +inf (exceeds every finite candidate)
            w0 = (used_m & 0x01u) ? INF32 : w0;
            w1 = (used_m & 0x02u) ? INF32 : w1;
            w2 = (used_m & 0x04u) ? INF32 : w2;
            w3 = (used_m & 0x08u) ? INF32 : w3;
            w4 = (used_m & 0x10u) ? INF32 : w4;
            w5 = (used_m & 0x20u) ? INF32 : w5;
            w6 = (used_m & 0x40u) ? INF32 : w6;
            w7 = (used_m & 0x80u) ? INF32 : w7;

            // ---- f64 candidates (reference order: (c - u) - v)
            double d0 = ((double)w0 - urow) - v0;
            double d1 = ((double)w1 - urow) - v1;
            double d2 = ((double)w2 - urow) - v2;
            double d3 = ((double)w3 - urow) - v3;
            double d4 = ((double)w4 - urow) - v4;
            double d5 = ((double)w5 - urow) - v5;
            double d6 = ((double)w6 - urow) - v6;
            double d7 = ((double)w7 - urow) - v7;

            // ---- local 8->1 f64 tree (strict <, ties -> lower slot)
            double  ka = (d1 < d0) ? d1 : d0;  uint32_t sa = (d1 < d0) ? 1u : 0u;
            double  kb = (d3 < d2) ? d3 : d2;  uint32_t sb = (d3 < d2) ? 3u : 2u;
            double  kx = (d5 < d4) ? d5 : d4;  uint32_t sx = (d5 < d4) ? 5u : 4u;
            double  kd = (d7 < d6) ? d7 : d6;  uint32_t sd = (d7 < d6) ? 7u : 6u;
            double  ke = (kb < ka) ? kb : ka;  uint32_t se = (kb < ka) ? sb : sa;
            double  kf = (kd < kx) ? kd : kx;  uint32_t sf = (kd < kx) ? sd : sx;
            double  bv = (kf < ke) ? kf : ke;  uint32_t bslot = (kf < ke) ? sf : se;

            // ---- sortable key of the lane-best (order(key) == order(f64))
            uint64_t kb64 = (uint64_t)__double_as_longlong(bv);
            kb64 ^= (kb64 >> 63) ? 0xFFFFFFFFFFFFFFFFull : 0x8000000000000000ull;
            uint32_t khi = (uint32_t)(kb64 >> 32);
            uint32_t klo = (uint32_t)kb64;

            // ---- per-lane owner pre-select (overlaps the reduce)
            int own_pre;
            SEL8I(bslot, p0,p1,p2,p3,p4,p5,p6,p7, own_pre);

            // ---- phase A: wave min of hi32
            uint32_t Mhi = (uint32_t)__builtin_amdgcn_readlane(
                               (int)wave_umin_lane63(khi), 63);
            unsigned long long tied_hi = __ballot(khi == Mhi);

            int lane1; uint32_t Mlo;
            if (__builtin_popcountll(tied_hi) == 1) {      // unique hi-min
                lane1 = (int)__builtin_ctzll(tied_hi);
                Mlo = (uint32_t)__builtin_amdgcn_readlane((int)klo, lane1);
            } else {                                       // phase B on lo32
                uint32_t kl2 = (khi == Mhi) ? klo : 0xFFFFFFFFu;
                Mlo = (uint32_t)__builtin_amdgcn_readlane(
                          (int)wave_umin_lane63(kl2), 63);
                lane1 = (int)__builtin_ctzll(__ballot(khi == Mhi && klo == Mlo));
            }

            int slot1 = __builtin_amdgcn_readlane((int)bslot, lane1);
            int owner = __builtin_amdgcn_readlane(own_pre, lane1);

            // ---- delta = min value (inverse key map; wave-uniform)
            uint64_t M = ((uint64_t)Mhi << 32) | Mlo;
            uint64_t db = (M >> 63) ? (M ^ 0x8000000000000000ull) : ~M;
            double delta = __longlong_as_double((long long)db);

            if (owner < 0) {     // free column: terminal updates + assign
                u0 += (chain_m & 0x01u) ? delta : 0.0;
                u1 += (chain_m & 0x02u) ? delta : 0.0;
                u2 += (chain_m & 0x04u) ? delta : 0.0;
                u3 += (chain_m & 0x08u) ? delta : 0.0;
                u4 += (chain_m & 0x10u) ? delta : 0.0;
                u5 += (chain_m & 0x20u) ? delta : 0.0;
                u6 += (chain_m & 0x40u) ? delta : 0.0;
                u7 += (chain_m & 0x80u) ? delta : 0.0;
                v0 -= (used_m  & 0x01u) ? delta : 0.0;
                v1 -= (used_m  & 0x02u) ? delta : 0.0;
                v2 -= (used_m  & 0x04u) ? delta : 0.0;
                v3 -= (used_m  & 0x08u) ? delta : 0.0;
                v4 -= (used_m  & 0x10u) ? delta : 0.0;
                v5 -= (used_m  & 0x20u) ? delta : 0.0;
                v6 -= (used_m  & 0x40u) ? delta : 0.0;
                v7 -= (used_m  & 0x80u) ? delta : 0.0;
                bool mine = (t == lane1);
                p0 = (mine && slot1 == 0) ? i : p0;
                p1 = (mine && slot1 == 1) ? i : p1;
                p2 = (mine && slot1 == 2) ? i : p2;
                p3 = (mine && slot1 == 3) ? i : p3;
                p4 = (mine && slot1 == 4) ? i : p4;
                p5 = (mine && slot1 == 5) ? i : p5;
                p6 = (mine && slot1 == 6) ? i : p6;
                p7 = (mine && slot1 == 7) ? i : p7;
                break;
            }

            // ---- hop: fetch next row scalars FIRST (serial chain), then
            // bookkeeping (off-chain; owner's u/chain untouched this step)
            ROW_SCALARS(owner);

            u0 += (chain_m & 0x01u) ? delta : 0.0;
            u1 += (chain_m & 0x02u) ? delta : 0.0;
            u2 += (chain_m & 0x04u) ? delta : 0.0;
            u3 += (chain_m & 0x08u) ? delta : 0.0;
            u4 += (chain_m & 0x10u) ? delta : 0.0;
            u5 += (chain_m & 0x20u) ? delta : 0.0;
            u6 += (chain_m & 0x40u) ? delta : 0.0;
            u7 += (chain_m & 0x80u) ? delta : 0.0;
            v0 -= (used_m  & 0x01u) ? delta : 0.0;
            v1 -= (used_m  & 0x02u) ? delta : 0.0;
            v2 -= (used_m  & 0x04u) ? delta : 0.0;
            v3 -= (used_m  & 0x08u) ? delta : 0.0;
            v4 -= (used_m  & 0x10u) ? delta : 0.0;
            v5 -= (used_m  & 0x20u) ? delta : 0.0;
            v6 -= (used_m  & 0x40u) ? delta : 0.0;
            v7 -= (used_m  & 0x80u) ? delta : 0.0;

            used_m  |= (t == lane1)        ? (1u << slot1)       : 0u;
            chain_m |= (t == (owner >> 3)) ? (1u << (owner & 7)) : 0u;
        }
    }

    // col_of_row[p_col[j]] = j   (j = 8t + k)
    gt_idx[b * N_ + p0] = (float)(base);
    gt_idx[b * N_ + p1] = (float)(base + 1);
    gt_idx[b * N_ + p2] = (float)(base + 2);
    gt_idx[b * N_ + p3] = (float)(base + 3);
    gt_idx[b * N_ + p4] = (float)(base + 4);
    gt_idx[b * N_ + p5] = (float)(base + 5);
    gt_idx[b * N_ + p6] = (float)(base + 6);
    gt_idx[b * N_ + p7] = (float)(base + 7);
}

// ---------------------------------------------------------------------------
extern "C" void kernel_launch(void* const* d_in, const int* in_sizes, int n_in,
                              void* d_out, int out_size, void* d_ws, size_t ws_size,
                              hipStream_t stream)
{
    const float* logits   = (const float*)d_in[0];   // (B,N)   f32
    const float* pred_pts = (const float*)d_in[1];   // (B,N,2) f32
    const float* gt_pts   = (const float*)d_in[2];   // (B,N,2) f32
    // d_in[3] = gt_mask (all true) - unused

    float* out      = (float*)d_out;
    float* pred_idx = out;                    // B*N
    float* gt_idx   = out + B_ * N_;          // B*N
    float* C        = out + 2 * B_ * N_;      // B*N*N
    float* cc       = (float*)d_ws;           // B*N scratch

    class_cost_kernel<<<(B_ * N_ + 255) / 256, 256, 0, stream>>>(logits, cc);
    cost_kernel<<<B_ * N_, N_, 0, stream>>>(cc, pred_pts, gt_pts, C);
    solve_kernel<<<B_, 64, 0, stream>>>(cc, pred_pts, gt_pts, pred_idx, gt_idx);
}